// Round 1
// baseline (405.010 us; speedup 1.0000x reference)
//
#include <hip/hip_runtime.h>
#include <math.h>

#define NNODE 2048
#define NEDGE 32768
#define HID   128
#define KIN   260          // 2*H + 4 edge feats
#define NMAT  (NNODE * NNODE)

// ---------------------------------------------------------------------------
// init: adj_idx = -1, agg/wsum/rsum/cnt = 0   (ws is poisoned 0xAA each call)
// ---------------------------------------------------------------------------
__global__ __launch_bounds__(256) void init_kernel(int* __restrict__ adj_idx,
                                                   float* __restrict__ agg,
                                                   float* __restrict__ wsum,
                                                   float* __restrict__ rsum,
                                                   float* __restrict__ cnt) {
    int gid = blockIdx.x * 256 + threadIdx.x;
    int stride = gridDim.x * 256;
    for (int i = gid; i < NMAT; i += stride) adj_idx[i] = -1;
    if (gid < NNODE * HID) agg[gid] = 0.0f;
    if (gid < NNODE) { wsum[gid] = 0.0f; rsum[gid] = 0.0f; cnt[gid] = 0.0f; }
}

// ---------------------------------------------------------------------------
// scatter: last-edge-index-wins for duplicate (src,dst) pairs
// ---------------------------------------------------------------------------
__global__ __launch_bounds__(256) void scatter_kernel(const int* __restrict__ ei,
                                                      int* __restrict__ adj_idx) {
    int e = blockIdx.x * 256 + threadIdx.x;
    if (e < NEDGE) {
        int s = ei[e];
        int d = ei[NEDGE + e];
        atomicMax(&adj_idx[s * NNODE + d], e);
    }
}

// ---------------------------------------------------------------------------
// build adj_val (row-major) and adjT (transpose) via 32x32 LDS tiles
// ---------------------------------------------------------------------------
__global__ __launch_bounds__(256) void build_vals_kernel(const int* __restrict__ adj_idx,
                                                         const float* __restrict__ dist,
                                                         float* __restrict__ adj_val,
                                                         float* __restrict__ adjT,
                                                         int do_transpose) {
    __shared__ float tile[32][33];
    int bx = blockIdx.x & 63;   // col tile (2048/32 = 64)
    int by = blockIdx.x >> 6;   // row tile
    int tx = threadIdx.x & 31;
    int ty = threadIdx.x >> 5;  // 0..7
    int c = bx * 32 + tx;
    #pragma unroll
    for (int i = 0; i < 32; i += 8) {
        int r = by * 32 + ty + i;
        int idx = adj_idx[r * NNODE + c];
        float v = (idx >= 0) ? dist[idx] : -1.0f;
        adj_val[r * NNODE + c] = v;
        tile[ty + i][tx] = v;
    }
    if (do_transpose) {
        __syncthreads();
        int c2 = by * 32 + tx;
        #pragma unroll
        for (int i = 0; i < 32; i += 8) {
            int r2 = bx * 32 + ty + i;
            adjT[r2 * NNODE + c2] = tile[tx][ty + i];
        }
    }
}

// ---------------------------------------------------------------------------
// residuals: one wave (64 lanes) per edge, scan all B.
// USE_T=1: coalesced row reads of adj_val and adjT.
// USE_T=0 fallback (small ws): gather column of adj_val directly.
// Also accumulates r_sum[dst] and cnt[dst].
// ---------------------------------------------------------------------------
template <int USE_T>
__global__ __launch_bounds__(256) void residual_kernel(const int* __restrict__ ei,
                                                       const float* __restrict__ dist,
                                                       const float* __restrict__ adj_val,
                                                       const float* __restrict__ adjT,
                                                       float* __restrict__ res_out,
                                                       float* __restrict__ rsum,
                                                       float* __restrict__ cnt) {
    int wave = threadIdx.x >> 6;
    int lane = threadIdx.x & 63;
    int e = blockIdx.x * 4 + wave;
    int A = ei[e];
    int C = ei[NEDGE + e];
    float sum = 0.0f, count = 0.0f;
    const float4* rowA = (const float4*)(adj_val + (size_t)A * NNODE);
    if (USE_T) {
        const float4* colC = (const float4*)(adjT + (size_t)C * NNODE);
        for (int i = lane; i < NNODE / 4; i += 64) {
            float4 a = rowA[i];
            float4 b = colC[i];
            if (a.x >= 0.0f && b.x >= 0.0f) { sum += a.x + b.x; count += 1.0f; }
            if (a.y >= 0.0f && b.y >= 0.0f) { sum += a.y + b.y; count += 1.0f; }
            if (a.z >= 0.0f && b.z >= 0.0f) { sum += a.z + b.z; count += 1.0f; }
            if (a.w >= 0.0f && b.w >= 0.0f) { sum += a.w + b.w; count += 1.0f; }
        }
    } else {
        for (int i = lane; i < NNODE / 4; i += 64) {
            float4 a = rowA[i];
            int B = i * 4;
            float b0 = adj_val[(size_t)(B + 0) * NNODE + C];
            float b1 = adj_val[(size_t)(B + 1) * NNODE + C];
            float b2 = adj_val[(size_t)(B + 2) * NNODE + C];
            float b3 = adj_val[(size_t)(B + 3) * NNODE + C];
            if (a.x >= 0.0f && b0 >= 0.0f) { sum += a.x + b0; count += 1.0f; }
            if (a.y >= 0.0f && b1 >= 0.0f) { sum += a.y + b1; count += 1.0f; }
            if (a.z >= 0.0f && b2 >= 0.0f) { sum += a.z + b2; count += 1.0f; }
            if (a.w >= 0.0f && b3 >= 0.0f) { sum += a.w + b3; count += 1.0f; }
        }
    }
    #pragma unroll
    for (int off = 32; off > 0; off >>= 1) {
        sum += __shfl_down(sum, off, 64);
        count += __shfl_down(count, off, 64);
    }
    if (lane == 0) {
        float d = dist[e];
        float mean = (count > 0.0f) ? (sum / count) : d;
        float r = fabsf(d - mean);
        res_out[e] = r;
        atomicAdd(&rsum[C], r);
        atomicAdd(&cnt[C], 1.0f);
    }
}

// ---------------------------------------------------------------------------
// message MLP (E x 260 -> relu 128 -> 128) fused with weighted aggregation.
// 16 edges/block, 256 threads: thread = (edge el = tid>>4, jgroup = tid&15),
// 8 output accumulators each. Weights staged in 32-row LDS tiles.
// ---------------------------------------------------------------------------
__global__ __launch_bounds__(256) void msg_kernel(const float* __restrict__ mu,
                                                  const float* __restrict__ sigma,
                                                  const int* __restrict__ ei,
                                                  const float* __restrict__ dist,
                                                  const float* __restrict__ conf,
                                                  const float* __restrict__ angle,
                                                  const float* __restrict__ ddiff,
                                                  const float* __restrict__ w1,
                                                  const float* __restrict__ b1,
                                                  const float* __restrict__ w2,
                                                  const float* __restrict__ b2,
                                                  const float* __restrict__ res,
                                                  float* __restrict__ agg,
                                                  float* __restrict__ wsum) {
    __shared__ float xs[16][KIN];      // 16.6 KB
    __shared__ float wt[32 * HID];     // 16 KB
    __shared__ float hs[16][132];      // 8.25 KB (padded: no bank conflict)
    __shared__ int   sidx[32];
    __shared__ float swt[16];
    int tid = threadIdx.x;
    int e0 = blockIdx.x * 16;
    if (tid < 16) {
        sidx[tid] = ei[e0 + tid];               // src
        sidx[16 + tid] = ei[NEDGE + e0 + tid];  // dst
        swt[tid] = expf(-res[e0 + tid]);
    }
    __syncthreads();
    {
        int el = tid >> 4;
        int l = tid & 15;
        int s = sidx[el];
        const float* murow = mu + (size_t)s * HID;
        const float* sgrow = sigma + (size_t)s * HID;
        for (int k = l; k < HID; k += 16) {
            xs[el][k] = murow[k];
            xs[el][HID + k] = sgrow[k];
        }
        if (l == 0) {
            int e = e0 + el;
            xs[el][256] = dist[e];
            xs[el][257] = conf[e];
            xs[el][258] = angle[e];
            xs[el][259] = ddiff[e];
        }
    }

    int el = tid >> 4;
    int jg = tid & 15;
    int j0 = jg * 8;
    float acc[8];
    #pragma unroll
    for (int r = 0; r < 8; ++r) acc[r] = b1[j0 + r];

    for (int k0 = 0; k0 < KIN; k0 += 32) {
        int rows = (KIN - k0 < 32) ? (KIN - k0) : 32;
        __syncthreads();
        for (int i = tid; i < rows * (HID / 4); i += 256)
            ((float4*)wt)[i] = ((const float4*)(w1 + (size_t)k0 * HID))[i];
        __syncthreads();
        for (int kk = 0; kk < rows; ++kk) {
            float xv = xs[el][k0 + kk];
            const float* wr = wt + kk * HID + j0;
            #pragma unroll
            for (int r = 0; r < 8; ++r) acc[r] = fmaf(xv, wr[r], acc[r]);
        }
    }
    #pragma unroll
    for (int r = 0; r < 8; ++r) hs[el][j0 + r] = fmaxf(acc[r], 0.0f);

    #pragma unroll
    for (int r = 0; r < 8; ++r) acc[r] = b2[j0 + r];
    for (int k0 = 0; k0 < HID; k0 += 32) {
        __syncthreads();
        for (int i = tid; i < 32 * (HID / 4); i += 256)
            ((float4*)wt)[i] = ((const float4*)(w2 + (size_t)k0 * HID))[i];
        __syncthreads();
        for (int kk = 0; kk < 32; ++kk) {
            float xv = hs[el][k0 + kk];
            const float* wr = wt + kk * HID + j0;
            #pragma unroll
            for (int r = 0; r < 8; ++r) acc[r] = fmaf(xv, wr[r], acc[r]);
        }
    }
    float we = swt[el];
    int d = sidx[16 + el];
    float* aggrow = agg + (size_t)d * HID + j0;
    #pragma unroll
    for (int r = 0; r < 8; ++r) atomicAdd(&aggrow[r], acc[r] * we);
    if (jg == 0) atomicAdd(&wsum[d], we);
}

// ---------------------------------------------------------------------------
// node mu MLP: mu_new = mu + mlp(agg_norm)
// ---------------------------------------------------------------------------
__global__ __launch_bounds__(256) void mu_kernel(const float* __restrict__ mu,
                                                 const float* __restrict__ agg,
                                                 const float* __restrict__ wsum,
                                                 const float* __restrict__ w1,
                                                 const float* __restrict__ b1,
                                                 const float* __restrict__ w2,
                                                 const float* __restrict__ b2,
                                                 float* __restrict__ out) {
    __shared__ float xs[16][132];
    __shared__ float wt[32 * HID];
    __shared__ float hs[16][132];
    int tid = threadIdx.x;
    int n0 = blockIdx.x * 16;
    {
        int nl = tid >> 4, l = tid & 15;
        int n = n0 + nl;
        float inv = 1.0f / fmaxf(wsum[n], 1e-8f);
        for (int k = l; k < HID; k += 16)
            xs[nl][k] = agg[(size_t)n * HID + k] * inv;
    }
    __syncthreads();
    int nl = tid >> 4, jg = tid & 15, j0 = jg * 8;
    float acc[8];
    #pragma unroll
    for (int r = 0; r < 8; ++r) acc[r] = b1[j0 + r];
    for (int k0 = 0; k0 < HID; k0 += 32) {
        __syncthreads();
        for (int i = tid; i < 32 * (HID / 4); i += 256)
            ((float4*)wt)[i] = ((const float4*)(w1 + (size_t)k0 * HID))[i];
        __syncthreads();
        for (int kk = 0; kk < 32; ++kk) {
            float xv = xs[nl][k0 + kk];
            const float* wr = wt + kk * HID + j0;
            #pragma unroll
            for (int r = 0; r < 8; ++r) acc[r] = fmaf(xv, wr[r], acc[r]);
        }
    }
    #pragma unroll
    for (int r = 0; r < 8; ++r) hs[nl][j0 + r] = fmaxf(acc[r], 0.0f);
    #pragma unroll
    for (int r = 0; r < 8; ++r) acc[r] = b2[j0 + r];
    for (int k0 = 0; k0 < HID; k0 += 32) {
        __syncthreads();
        for (int i = tid; i < 32 * (HID / 4); i += 256)
            ((float4*)wt)[i] = ((const float4*)(w2 + (size_t)k0 * HID))[i];
        __syncthreads();
        for (int kk = 0; kk < 32; ++kk) {
            float xv = hs[nl][k0 + kk];
            const float* wr = wt + kk * HID + j0;
            #pragma unroll
            for (int r = 0; r < 8; ++r) acc[r] = fmaf(xv, wr[r], acc[r]);
        }
    }
    int n = n0 + nl;
    #pragma unroll
    for (int r = 0; r < 8; ++r)
        out[(size_t)n * HID + j0 + r] = mu[(size_t)n * HID + j0 + r] + acc[r];
}

// ---------------------------------------------------------------------------
// node sigma MLP: sigma_new = softplus(mlp([agg_norm, mean_r]))  (K = 129)
// ---------------------------------------------------------------------------
__global__ __launch_bounds__(256) void sig_kernel(const float* __restrict__ agg,
                                                  const float* __restrict__ wsum,
                                                  const float* __restrict__ rsum,
                                                  const float* __restrict__ cnt,
                                                  const float* __restrict__ w1,
                                                  const float* __restrict__ b1,
                                                  const float* __restrict__ w2,
                                                  const float* __restrict__ b2,
                                                  float* __restrict__ out) {
    __shared__ float xs[16][132];
    __shared__ float wt[32 * HID];
    __shared__ float hs[16][132];
    int tid = threadIdx.x;
    int n0 = blockIdx.x * 16;
    {
        int nl = tid >> 4, l = tid & 15;
        int n = n0 + nl;
        float inv = 1.0f / fmaxf(wsum[n], 1e-8f);
        for (int k = l; k < HID; k += 16)
            xs[nl][k] = agg[(size_t)n * HID + k] * inv;
        if (l == 0)
            xs[nl][HID] = rsum[n] / fmaxf(cnt[n], 1.0f);
    }
    __syncthreads();
    int nl = tid >> 4, jg = tid & 15, j0 = jg * 8;
    float acc[8];
    #pragma unroll
    for (int r = 0; r < 8; ++r) acc[r] = b1[j0 + r];
    for (int k0 = 0; k0 < 129; k0 += 32) {
        int rows = (129 - k0 < 32) ? (129 - k0) : 32;
        __syncthreads();
        for (int i = tid; i < rows * (HID / 4); i += 256)
            ((float4*)wt)[i] = ((const float4*)(w1 + (size_t)k0 * HID))[i];
        __syncthreads();
        for (int kk = 0; kk < rows; ++kk) {
            float xv = xs[nl][k0 + kk];
            const float* wr = wt + kk * HID + j0;
            #pragma unroll
            for (int r = 0; r < 8; ++r) acc[r] = fmaf(xv, wr[r], acc[r]);
        }
    }
    #pragma unroll
    for (int r = 0; r < 8; ++r) hs[nl][j0 + r] = fmaxf(acc[r], 0.0f);
    #pragma unroll
    for (int r = 0; r < 8; ++r) acc[r] = b2[j0 + r];
    for (int k0 = 0; k0 < HID; k0 += 32) {
        __syncthreads();
        for (int i = tid; i < 32 * (HID / 4); i += 256)
            ((float4*)wt)[i] = ((const float4*)(w2 + (size_t)k0 * HID))[i];
        __syncthreads();
        for (int kk = 0; kk < 32; ++kk) {
            float xv = hs[nl][k0 + kk];
            const float* wr = wt + kk * HID + j0;
            #pragma unroll
            for (int r = 0; r < 8; ++r) acc[r] = fmaf(xv, wr[r], acc[r]);
        }
    }
    int n = n0 + nl;
    #pragma unroll
    for (int r = 0; r < 8; ++r) {
        float x = acc[r];
        // jax.nn.softplus: max(x,0) + log1p(exp(-|x|))
        out[(size_t)n * HID + j0 + r] = fmaxf(x, 0.0f) + log1pf(expf(-fabsf(x)));
    }
}

// ---------------------------------------------------------------------------
extern "C" void kernel_launch(void* const* d_in, const int* in_sizes, int n_in,
                              void* d_out, int out_size, void* d_ws, size_t ws_size,
                              hipStream_t stream) {
    const float* mu     = (const float*)d_in[0];
    const float* sigma  = (const float*)d_in[1];
    const int*   ei     = (const int*)d_in[2];
    const float* dist   = (const float*)d_in[3];
    const float* conf   = (const float*)d_in[4];
    const float* angle  = (const float*)d_in[5];
    const float* ddiff  = (const float*)d_in[6];
    const float* msg_w1 = (const float*)d_in[7];
    const float* msg_b1 = (const float*)d_in[8];
    const float* msg_w2 = (const float*)d_in[9];
    const float* msg_b2 = (const float*)d_in[10];
    const float* mu_w1  = (const float*)d_in[11];
    const float* mu_b1  = (const float*)d_in[12];
    const float* mu_w2  = (const float*)d_in[13];
    const float* mu_b2  = (const float*)d_in[14];
    const float* sig_w1 = (const float*)d_in[15];
    const float* sig_b1 = (const float*)d_in[16];
    const float* sig_w2 = (const float*)d_in[17];
    const float* sig_b2 = (const float*)d_in[18];

    float* out_mu  = (float*)d_out;
    float* out_sig = out_mu + (size_t)NNODE * HID;
    float* out_res = out_sig + (size_t)NNODE * HID;

    char* ws = (char*)d_ws;
    int*   adj_idx = (int*)ws;
    float* adj_val = (float*)(ws + (size_t)NMAT * 4);
    float* adjT    = (float*)(ws + (size_t)NMAT * 8);

    size_t tail_bytes = ((size_t)NNODE * HID + 3 * NNODE) * 4;
    size_t need_full  = (size_t)NMAT * 12 + tail_bytes;
    int useT = (ws_size >= need_full) ? 1 : 0;

    float* agg  = (float*)(ws + (useT ? (size_t)NMAT * 12 : (size_t)NMAT * 8));
    float* wsum = agg + (size_t)NNODE * HID;
    float* rsum = wsum + NNODE;
    float* cntb = rsum + NNODE;

    hipLaunchKernelGGL(init_kernel, dim3(4096), dim3(256), 0, stream,
                       adj_idx, agg, wsum, rsum, cntb);
    hipLaunchKernelGGL(scatter_kernel, dim3(NEDGE / 256), dim3(256), 0, stream,
                       ei, adj_idx);
    hipLaunchKernelGGL(build_vals_kernel, dim3(64 * 64), dim3(256), 0, stream,
                       adj_idx, dist, adj_val, adjT, useT);
    if (useT)
        hipLaunchKernelGGL((residual_kernel<1>), dim3(NEDGE / 4), dim3(256), 0, stream,
                           ei, dist, adj_val, adjT, out_res, rsum, cntb);
    else
        hipLaunchKernelGGL((residual_kernel<0>), dim3(NEDGE / 4), dim3(256), 0, stream,
                           ei, dist, adj_val, adjT, out_res, rsum, cntb);
    hipLaunchKernelGGL(msg_kernel, dim3(NEDGE / 16), dim3(256), 0, stream,
                       mu, sigma, ei, dist, conf, angle, ddiff,
                       msg_w1, msg_b1, msg_w2, msg_b2, out_res, agg, wsum);
    hipLaunchKernelGGL(mu_kernel, dim3(NNODE / 16), dim3(256), 0, stream,
                       mu, agg, wsum, mu_w1, mu_b1, mu_w2, mu_b2, out_mu);
    hipLaunchKernelGGL(sig_kernel, dim3(NNODE / 16), dim3(256), 0, stream,
                       agg, wsum, rsum, cntb, sig_w1, sig_b1, sig_w2, sig_b2, out_sig);
}